// Round 7
// baseline (653.386 us; speedup 1.0000x reference)
//
#include <hip/hip_runtime.h>

// Output layout (float*, concatenated in reference return order):
//   z_q_out : 64*64*64*64 = 16,777,216 floats  @ [0, 16777216)
//   loss    : 1 float                          @ [16777216]
//   idx_out : 64*64*64   =    262,144 floats   @ [16777217, 17039361)
//   perplex : 1 float                          @ [17039361]
#define ZQ_OFF    0
#define LOSS_OFF  16777216
#define IDX_OFF   16777217
#define PERP_OFF  17039361

#define NPOINTS   262144      // B*H*W
#define NELEM     16777216    // B*C*H*W
#define KTILE     256         // codes per LDS tile: 256*64*4B = 64 KB

// ws layout: [0,2048) float embnorm[512]; [2048,4096) int hist[512]; [4096,4104) double lossacc

// ---------------- kernel 0: codebook norms + zero accumulators ----------------
__global__ void prep_kernel(const float* __restrict__ emb,
                            float* __restrict__ embnorm,
                            int* __restrict__ hist,
                            double* __restrict__ lossacc) {
    int k = threadIdx.x;          // 512 threads, 1 block
    hist[k] = 0;
    const float* e = emb + (k << 6);
    float s = 0.f;
    #pragma unroll
    for (int d = 0; d < 64; ++d) s += e[d] * e[d];
    embnorm[k] = s;
    if (k == 0) *lossacc = 0.0;
}

// ---------------- kernel 1: argmin + z_q(STE) + idx + hist + loss partials ----------------
// R5 post-mortem: emb-operand delivery (scalar-cache/VMEM re-stream of the
// 128KB codebook per thread) + partial zv scratch-spill (VGPR=56, +8MB write)
// bound the sweep at 462us / VALUBusy 66%. Fix: codebook staged in LDS, read
// with WAVE-UNIFORM addresses (ds_read_b128 broadcast: conflict-free, no K$).
__global__ __launch_bounds__(1024, 4) void vq_kernel(const float* __restrict__ z,
                                                 const float* __restrict__ emb,
                                                 const float* __restrict__ embnorm,
                                                 float* __restrict__ out,
                                                 int* __restrict__ hist,
                                                 double* __restrict__ lossacc) {
    // 256 blocks x 1024 threads; thread = one (b,h,w) point; block = b fixed, 16 h-rows.
    __shared__ __align__(16) float elds[KTILE * 64];   // 64 KB, reused as wsum at the end
    const int tid = threadIdx.x;
    const int bid = blockIdx.x;
    const int b  = bid >> 2;                       // 64 b values
    const int h  = ((bid & 3) << 4) + (tid >> 6);  // 16 rows per block
    const int w  = tid & 63;

    // Load this point's 64-dim vector; lanes (w=0..63) consecutive -> coalesced per channel.
    const float* zp = z + ((size_t)b << 18) + ((size_t)h << 6) + w;  // + c*4096
    float zv[64];
    float z2 = 0.f;
    #pragma unroll
    for (int d = 0; d < 64; ++d) {
        float v = zp[(size_t)d << 12];
        zv[d] = v;
        z2 += v * v;
    }

    float best = 3.4e38f;
    int   bidx = 0;

    for (int t = 0; t < 512; t += KTILE) {
        // ---- stage tile: 16384 floats, 1024 threads x 4 float4, coalesced ----
        __syncthreads();   // previous tile's readers done before overwrite
        const float4* esrc = (const float4*)(emb + ((size_t)t << 6));
        float4*       edst = (float4*)elds;
        #pragma unroll
        for (int i = 0; i < 4; ++i)
            edst[tid + (i << 10)] = esrc[tid + (i << 10)];
        __syncthreads();

        // ---- sweep tile; all lanes at the same k -> uniform-addr LDS broadcast ----
        for (int k0 = 0; k0 < KTILE; k0 += 4) {
            const float* e0 = elds + (k0 << 6);
            float a0 = 0.f, a1 = 0.f, a2 = 0.f, a3 = 0.f;
            #pragma unroll
            for (int dc = 0; dc < 64; dc += 4) {
                float4 e0v = *(const float4*)(e0 + dc);
                float4 e1v = *(const float4*)(e0 + 64 + dc);
                float4 e2v = *(const float4*)(e0 + 128 + dc);
                float4 e3v = *(const float4*)(e0 + 192 + dc);
                // sequential-d single-chain accumulation: bit-identical to the
                // passing R3 kernel (absmax 0.0)
                a0 += zv[dc] * e0v.x; a0 += zv[dc+1] * e0v.y; a0 += zv[dc+2] * e0v.z; a0 += zv[dc+3] * e0v.w;
                a1 += zv[dc] * e1v.x; a1 += zv[dc+1] * e1v.y; a1 += zv[dc+2] * e1v.z; a1 += zv[dc+3] * e1v.w;
                a2 += zv[dc] * e2v.x; a2 += zv[dc+1] * e2v.y; a2 += zv[dc+2] * e2v.z; a2 += zv[dc+3] * e2v.w;
                a3 += zv[dc] * e3v.x; a3 += zv[dc+1] * e3v.y; a3 += zv[dc+2] * e3v.z; a3 += zv[dc+3] * e3v.w;
            }
            int kk = t + k0;
            // same formula as reference: ||z||^2 + ||e||^2 - 2 z.e
            float d0 = z2 + embnorm[kk    ] - 2.f * a0;
            float d1 = z2 + embnorm[kk + 1] - 2.f * a1;
            float d2 = z2 + embnorm[kk + 2] - 2.f * a2;
            float d3 = z2 + embnorm[kk + 3] - 2.f * a3;
            // strict < in ascending k preserves first-min (reference argmin tie rule)
            if (d0 < best) { best = d0; bidx = kk;     }
            if (d1 < best) { best = d1; bidx = kk + 1; }
            if (d2 < best) { best = d2; bidx = kk + 2; }
            if (d3 < best) { best = d3; bidx = kk + 3; }
        }
    }

    // idx output (as float) + histogram
    const size_t pidx = ((size_t)b << 12) + ((size_t)h << 6) + w;
    __builtin_nontemporal_store((float)bidx, &out[IDX_OFF + pidx]);
    atomicAdd(&hist[bidx], 1);

    // z_q straight-through write + loss partial.
    // Replicate reference rounding: diff = e - z (fp32); out = z + diff (fp32); loss term = diff^2.
    const float* eb = emb + ((size_t)bidx << 6);   // per-lane gather, L2-resident
    float* zqout = out + ((size_t)b << 18) + ((size_t)h << 6) + w;
    float lsum = 0.f;
    #pragma unroll
    for (int d = 0; d < 64; ++d) {
        float e    = eb[d];
        float diff = e - zv[d];
        lsum += diff * diff;
        // nt store: don't let the 64 MB z_q stream evict emb/z from L1/L2
        __builtin_nontemporal_store(zv[d] + diff, &zqout[(size_t)d << 12]);
    }

    // block-reduce lsum -> one double atomic per block (reuse elds as scratch)
    #pragma unroll
    for (int off = 32; off; off >>= 1) lsum += __shfl_down(lsum, off, 64);
    __syncthreads();                       // sweep reads of elds all done
    float* wsum = elds;
    if ((tid & 63) == 0) wsum[tid >> 6] = lsum;
    __syncthreads();
    if (tid == 0) {
        float s = 0.f;
        #pragma unroll
        for (int i = 0; i < 16; ++i) s += wsum[i];
        atomicAdd(lossacc, (double)s);
    }
}

// ---------------- kernel 2: finalize loss + perplexity ----------------
__global__ void fin_kernel(const int* __restrict__ hist,
                           const double* __restrict__ lossacc,
                           float* __restrict__ out) {
    int k = threadIdx.x;   // 512 threads, 1 block
    float avg = (float)hist[k] * (1.0f / 262144.0f);   // exact: cnt / 2^18
    float t = avg * logf(avg + 1e-10f);
    #pragma unroll
    for (int off = 32; off; off >>= 1) t += __shfl_down(t, off, 64);
    __shared__ float s[8];
    if ((k & 63) == 0) s[k >> 6] = t;
    __syncthreads();
    if (k == 0) {
        float S = 0.f;
        #pragma unroll
        for (int i = 0; i < 8; ++i) S += s[i];
        out[PERP_OFF] = expf(-S);
        out[LOSS_OFF] = (float)(1.25 * (*lossacc) / (double)NELEM);
    }
}

extern "C" void kernel_launch(void* const* d_in, const int* in_sizes, int n_in,
                              void* d_out, int out_size, void* d_ws, size_t ws_size,
                              hipStream_t stream) {
    const float* z   = (const float*)d_in[0];
    const float* emb = (const float*)d_in[1];
    float* out = (float*)d_out;

    float*  embnorm = (float*)d_ws;
    int*    hist    = (int*)((char*)d_ws + 2048);
    double* lossacc = (double*)((char*)d_ws + 4096);

    prep_kernel<<<1, 512, 0, stream>>>(emb, embnorm, hist, lossacc);
    vq_kernel<<<256, 1024, 0, stream>>>(z, emb, embnorm, out, hist, lossacc);
    fin_kernel<<<1, 512, 0, stream>>>(hist, lossacc, out);
}

// Round 8
// 565.208 us; speedup vs baseline: 1.1560x; 1.1560x over previous
//
#include <hip/hip_runtime.h>

// Output layout (float*, concatenated in reference return order):
//   z_q_out : 64*64*64*64 = 16,777,216 floats  @ [0, 16777216)
//   loss    : 1 float                          @ [16777216]
//   idx_out : 64*64*64   =    262,144 floats   @ [16777217, 17039361)
//   perplex : 1 float                          @ [17039361]
#define ZQ_OFF    0
#define LOSS_OFF  16777216
#define IDX_OFF   16777217
#define PERP_OFF  17039361

#define NPOINTS   262144      // B*H*W
#define NELEM     16777216    // B*C*H*W

// ws layout: [0,2048) float embnorm[512]; [2048,4096) int hist[512]; [4096,4104) double lossacc

// ---------------- kernel 0: codebook norms + zero accumulators ----------------
__global__ void prep_kernel(const float* __restrict__ emb,
                            float* __restrict__ embnorm,
                            int* __restrict__ hist,
                            double* __restrict__ lossacc) {
    int k = threadIdx.x;          // 512 threads, 1 block
    hist[k] = 0;
    const float* e = emb + (k << 6);
    float s = 0.f;
    #pragma unroll
    for (int d = 0; d < 64; ++d) s += e[d] * e[d];
    embnorm[k] = s;
    if (k == 0) *lossacc = 0.0;
}

// ---------------- kernel 1: argmin + z_q(STE) + idx + hist + loss partials ----------------
// History: R3 (K$/SMEM emb path) 462us, VALUBusy 66%, VGPR=60. R7 (LDS tile)
// 602us — LDS-pipe-bound: per-thread operand volume (128KB) x 16 waves/CU
// through one 128B/cyc LDS pipe = ~650us. SMEM path is right: s_load feeds
// v_fmac's SGPR operand slot, zero VALU-issue cost.
// Remaining R3 overhead was zv[] scratch-spill (VGPR stuck at 56-60, +8MB
// WRITE): the allocator targets 8 waves/EU unless the MAX is capped.
// amdgpu_waves_per_eu(4,4) pins 4 waves/EU -> 128-VGPR budget -> zv resident.
__global__ __launch_bounds__(256)
__attribute__((amdgpu_waves_per_eu(4, 4)))
void vq_kernel(const float* __restrict__ z,
               const float* __restrict__ emb,
               const float* __restrict__ embnorm,
               float* __restrict__ out,
               int* __restrict__ hist,
               double* __restrict__ lossacc) {
    // 1024 blocks x 256 threads; thread = one (b,h,w) point; block = b fixed, 4 h-rows.
    const int bid = blockIdx.x;
    const int b  = bid >> 4;                 // 64 b values
    const int h  = ((bid & 15) << 2) + (threadIdx.x >> 6); // 4 rows per block
    const int w  = threadIdx.x & 63;

    // Load this point's 64-dim vector; lanes (w=0..63) consecutive -> coalesced per channel.
    const float* zp = z + ((size_t)b << 18) + ((size_t)h << 6) + w;  // + c*4096
    float zv[64];
    float z2 = 0.f;
    #pragma unroll
    for (int d = 0; d < 64; ++d) {
        float v = zp[(size_t)d << 12];
        zv[d] = v;
        z2 += v * v;
    }

    // Sweep all 512 codes; emb addresses are wave-uniform -> s_load into SGPRs,
    // consumed as the scalar operand of v_fmac (no VALU-issue cost for delivery).
    float best = 3.4e38f;
    int   bidx = 0;
    for (int k0 = 0; k0 < 512; k0 += 4) {
        const float* e0 = emb + ((size_t)k0 << 6);
        float a0 = 0.f, a1 = 0.f, a2 = 0.f, a3 = 0.f;
        #pragma unroll
        for (int d = 0; d < 64; ++d) {
            float v = zv[d];
            a0 += v * e0[d];
            a1 += v * e0[d + 64];
            a2 += v * e0[d + 128];
            a3 += v * e0[d + 192];
        }
        // same formula as reference: ||z||^2 + ||e||^2 - 2 z.e
        float d0 = z2 + embnorm[k0    ] - 2.f * a0;
        float d1 = z2 + embnorm[k0 + 1] - 2.f * a1;
        float d2 = z2 + embnorm[k0 + 2] - 2.f * a2;
        float d3 = z2 + embnorm[k0 + 3] - 2.f * a3;
        // strict < in ascending k preserves first-min (reference argmin tie rule)
        if (d0 < best) { best = d0; bidx = k0;     }
        if (d1 < best) { best = d1; bidx = k0 + 1; }
        if (d2 < best) { best = d2; bidx = k0 + 2; }
        if (d3 < best) { best = d3; bidx = k0 + 3; }
    }

    // idx output (as float) + histogram
    const size_t pidx = ((size_t)b << 12) + ((size_t)h << 6) + w;
    __builtin_nontemporal_store((float)bidx, &out[IDX_OFF + pidx]);
    atomicAdd(&hist[bidx], 1);

    // z_q straight-through write + loss partial.
    // Replicate reference rounding: diff = e - z (fp32); out = z + diff (fp32); loss term = diff^2.
    const float* eb = emb + ((size_t)bidx << 6);   // per-lane gather, L2-resident
    float* zqout = out + ((size_t)b << 18) + ((size_t)h << 6) + w;
    float lsum = 0.f;
    #pragma unroll
    for (int d = 0; d < 64; ++d) {
        float e    = eb[d];
        float diff = e - zv[d];
        lsum += diff * diff;
        // nt store: don't let the 64 MB z_q stream evict emb/z from L1/L2
        __builtin_nontemporal_store(zv[d] + diff, &zqout[(size_t)d << 12]);
    }

    // block-reduce lsum -> one double atomic per block
    #pragma unroll
    for (int off = 32; off; off >>= 1) lsum += __shfl_down(lsum, off, 64);
    __shared__ float wsum[4];
    if ((threadIdx.x & 63) == 0) wsum[threadIdx.x >> 6] = lsum;
    __syncthreads();
    if (threadIdx.x == 0) {
        atomicAdd(lossacc, (double)(wsum[0] + wsum[1] + wsum[2] + wsum[3]));
    }
}

// ---------------- kernel 2: finalize loss + perplexity ----------------
__global__ void fin_kernel(const int* __restrict__ hist,
                           const double* __restrict__ lossacc,
                           float* __restrict__ out) {
    int k = threadIdx.x;   // 512 threads, 1 block
    float avg = (float)hist[k] * (1.0f / 262144.0f);   // exact: cnt / 2^18
    float t = avg * logf(avg + 1e-10f);
    #pragma unroll
    for (int off = 32; off; off >>= 1) t += __shfl_down(t, off, 64);
    __shared__ float s[8];
    if ((k & 63) == 0) s[k >> 6] = t;
    __syncthreads();
    if (k == 0) {
        float S = 0.f;
        #pragma unroll
        for (int i = 0; i < 8; ++i) S += s[i];
        out[PERP_OFF] = expf(-S);
        out[LOSS_OFF] = (float)(1.25 * (*lossacc) / (double)NELEM);
    }
}

extern "C" void kernel_launch(void* const* d_in, const int* in_sizes, int n_in,
                              void* d_out, int out_size, void* d_ws, size_t ws_size,
                              hipStream_t stream) {
    const float* z   = (const float*)d_in[0];
    const float* emb = (const float*)d_in[1];
    float* out = (float*)d_out;

    float*  embnorm = (float*)d_ws;
    int*    hist    = (int*)((char*)d_ws + 2048);
    double* lossacc = (double*)((char*)d_ws + 4096);

    prep_kernel<<<1, 512, 0, stream>>>(emb, embnorm, hist, lossacc);
    vq_kernel<<<1024, 256, 0, stream>>>(z, emb, embnorm, out, hist, lossacc);
    fin_kernel<<<1, 512, 0, stream>>>(hist, lossacc, out);
}

// Round 9
// 479.435 us; speedup vs baseline: 1.3628x; 1.1789x over previous
//
#include <hip/hip_runtime.h>

// Output layout (float*, concatenated in reference return order):
//   z_q_out : 64*64*64*64 = 16,777,216 floats  @ [0, 16777216)
//   loss    : 1 float                          @ [16777216]
//   idx_out : 64*64*64   =    262,144 floats   @ [16777217, 17039361)
//   perplex : 1 float                          @ [17039361]
#define ZQ_OFF    0
#define LOSS_OFF  16777216
#define IDX_OFF   16777217
#define PERP_OFF  17039361

#define NPOINTS   262144      // B*H*W
#define NELEM     16777216    // B*C*H*W

// ws layout: [0,2048) float embnorm[512]; [2048,4096) int hist[512]; [4096,4104) double lossacc

typedef float sf16 __attribute__((ext_vector_type(16)));
typedef float sf4  __attribute__((ext_vector_type(4)));

// 4 codebook rows x 16 d-values -> 64 SGPRs, plus (first chunk) 4 embnorms.
// The s_waitcnt lives INSIDE the asm so consumers can never be scheduled
// before the data lands (SMEM returns out-of-order; only lgkmcnt(0) is safe).
#define SLOAD5(E0,E1,E2,E3,EN,GB,NB,O0,O1,O2,O3)       \
  asm("s_load_dwordx16 %0, %5, " O0 "\n\t"             \
      "s_load_dwordx16 %1, %5, " O1 "\n\t"             \
      "s_load_dwordx16 %2, %5, " O2 "\n\t"             \
      "s_load_dwordx16 %3, %5, " O3 "\n\t"             \
      "s_load_dwordx4  %4, %6, 0x0\n\t"                \
      "s_waitcnt lgkmcnt(0)"                           \
      : "=s"(E0), "=s"(E1), "=s"(E2), "=s"(E3), "=s"(EN) \
      : "s"(GB), "s"(NB))

#define SLOAD4(E0,E1,E2,E3,GB,O0,O1,O2,O3)             \
  asm("s_load_dwordx16 %0, %4, " O0 "\n\t"             \
      "s_load_dwordx16 %1, %4, " O1 "\n\t"             \
      "s_load_dwordx16 %2, %4, " O2 "\n\t"             \
      "s_load_dwordx16 %3, %4, " O3 "\n\t"             \
      "s_waitcnt lgkmcnt(0)"                           \
      : "=s"(E0), "=s"(E1), "=s"(E2), "=s"(E3)         \
      : "s"(GB))

// 16 d-steps x 4 codes; SGPR operand rides in the v_fmac scalar slot (free).
// Per-accumulator chain order (d ascending) identical to the R3 kernel.
#define FMACHUNK(E0,E1,E2,E3,DC)                        \
  { _Pragma("unroll")                                   \
    for (int j = 0; j < 16; ++j) {                      \
      float v = zv[(DC) + j];                           \
      a0 += v * E0[j];                                  \
      a1 += v * E1[j];                                  \
      a2 += v * E2[j];                                  \
      a3 += v * E3[j];                                  \
    } }

// ---------------- kernel 0: codebook norms + zero accumulators ----------------
__global__ void prep_kernel(const float* __restrict__ emb,
                            float* __restrict__ embnorm,
                            int* __restrict__ hist,
                            double* __restrict__ lossacc) {
    int k = threadIdx.x;          // 512 threads, 1 block
    hist[k] = 0;
    const float* e = emb + (k << 6);
    float s = 0.f;
    #pragma unroll
    for (int d = 0; d < 64; ++d) s += e[d] * e[d];
    embnorm[k] = s;
    if (k == 0) *lossacc = 0.0;
}

// ---------------- kernel 1: argmin + z_q(STE) + idx + hist + loss partials ----------------
// R8 post-mortem: emb loads never scalarized -> per-lane VMEM broadcast +
// addr VALU = 3x essential VALU issue (328us busy vs 109us floor). Any
// vector-pipe delivery costs >=4B/FMA; the free path is the SGPR operand
// slot of v_fmac. Force it: inline-asm s_load_dwordx16 (wave-uniform rows).
// unroll 1 on the code loop kills the giant live ranges that spilled zv.
__global__ __launch_bounds__(256)
__attribute__((amdgpu_waves_per_eu(4, 4)))
void vq_kernel(const float* __restrict__ z,
               const float* __restrict__ emb,
               const float* __restrict__ embnorm,
               float* __restrict__ out,
               int* __restrict__ hist,
               double* __restrict__ lossacc) {
    // 1024 blocks x 256 threads; thread = one (b,h,w) point; block = b fixed, 4 h-rows.
    const int bid = blockIdx.x;
    const int b  = bid >> 4;                 // 64 b values
    const int h  = ((bid & 15) << 2) + (threadIdx.x >> 6); // 4 rows per block
    const int w  = threadIdx.x & 63;

    // Load this point's 64-dim vector; lanes (w=0..63) consecutive -> coalesced per channel.
    const float* zp = z + ((size_t)b << 18) + ((size_t)h << 6) + w;  // + c*4096
    float zv[64];
    float z2 = 0.f;
    #pragma unroll
    for (int d = 0; d < 64; ++d) {
        float v = zp[(size_t)d << 12];
        zv[d] = v;
        z2 += v * v;
    }

    float best = 3.4e38f;
    int   bidx = 0;
    #pragma unroll 1
    for (int k0 = 0; k0 < 512; k0 += 4) {
        const float* gb = emb + ((size_t)k0 << 6);   // uniform: SGPR pair
        const float* nb = embnorm + k0;              // uniform: SGPR pair
        sf16 E0, E1, E2, E3;
        sf4  EN;
        float a0 = 0.f, a1 = 0.f, a2 = 0.f, a3 = 0.f;

        SLOAD5(E0, E1, E2, E3, EN, gb, nb, "0x0",  "0x100", "0x200", "0x300");
        FMACHUNK(E0, E1, E2, E3, 0)
        SLOAD4(E0, E1, E2, E3, gb,        "0x40", "0x140", "0x240", "0x340");
        FMACHUNK(E0, E1, E2, E3, 16)
        SLOAD4(E0, E1, E2, E3, gb,        "0x80", "0x180", "0x280", "0x380");
        FMACHUNK(E0, E1, E2, E3, 32)
        SLOAD4(E0, E1, E2, E3, gb,        "0xC0", "0x1C0", "0x2C0", "0x3C0");
        FMACHUNK(E0, E1, E2, E3, 48)

        // same formula as reference: ||z||^2 + ||e||^2 - 2 z.e
        float d0 = z2 + EN[0] - 2.f * a0;
        float d1 = z2 + EN[1] - 2.f * a1;
        float d2 = z2 + EN[2] - 2.f * a2;
        float d3 = z2 + EN[3] - 2.f * a3;
        // strict < in ascending k preserves first-min (reference argmin tie rule)
        if (d0 < best) { best = d0; bidx = k0;     }
        if (d1 < best) { best = d1; bidx = k0 + 1; }
        if (d2 < best) { best = d2; bidx = k0 + 2; }
        if (d3 < best) { best = d3; bidx = k0 + 3; }
    }

    // idx output (as float) + histogram
    const size_t pidx = ((size_t)b << 12) + ((size_t)h << 6) + w;
    __builtin_nontemporal_store((float)bidx, &out[IDX_OFF + pidx]);
    atomicAdd(&hist[bidx], 1);

    // z_q straight-through write + loss partial.
    // Replicate reference rounding: diff = e - z (fp32); out = z + diff (fp32); loss term = diff^2.
    const float* eb = emb + ((size_t)bidx << 6);   // per-lane gather, L2-resident
    float* zqout = out + ((size_t)b << 18) + ((size_t)h << 6) + w;
    float lsum = 0.f;
    #pragma unroll
    for (int d = 0; d < 64; ++d) {
        float e    = eb[d];
        float diff = e - zv[d];
        lsum += diff * diff;
        // nt store: don't let the 64 MB z_q stream evict emb/z from L1/L2
        __builtin_nontemporal_store(zv[d] + diff, &zqout[(size_t)d << 12]);
    }

    // block-reduce lsum -> one double atomic per block
    #pragma unroll
    for (int off = 32; off; off >>= 1) lsum += __shfl_down(lsum, off, 64);
    __shared__ float wsum[4];
    if ((threadIdx.x & 63) == 0) wsum[threadIdx.x >> 6] = lsum;
    __syncthreads();
    if (threadIdx.x == 0) {
        atomicAdd(lossacc, (double)(wsum[0] + wsum[1] + wsum[2] + wsum[3]));
    }
}

// ---------------- kernel 2: finalize loss + perplexity ----------------
__global__ void fin_kernel(const int* __restrict__ hist,
                           const double* __restrict__ lossacc,
                           float* __restrict__ out) {
    int k = threadIdx.x;   // 512 threads, 1 block
    float avg = (float)hist[k] * (1.0f / 262144.0f);   // exact: cnt / 2^18
    float t = avg * logf(avg + 1e-10f);
    #pragma unroll
    for (int off = 32; off; off >>= 1) t += __shfl_down(t, off, 64);
    __shared__ float s[8];
    if ((k & 63) == 0) s[k >> 6] = t;
    __syncthreads();
    if (k == 0) {
        float S = 0.f;
        #pragma unroll
        for (int i = 0; i < 8; ++i) S += s[i];
        out[PERP_OFF] = expf(-S);
        out[LOSS_OFF] = (float)(1.25 * (*lossacc) / (double)NELEM);
    }
}

extern "C" void kernel_launch(void* const* d_in, const int* in_sizes, int n_in,
                              void* d_out, int out_size, void* d_ws, size_t ws_size,
                              hipStream_t stream) {
    const float* z   = (const float*)d_in[0];
    const float* emb = (const float*)d_in[1];
    float* out = (float*)d_out;

    float*  embnorm = (float*)d_ws;
    int*    hist    = (int*)((char*)d_ws + 2048);
    double* lossacc = (double*)((char*)d_ws + 4096);

    prep_kernel<<<1, 512, 0, stream>>>(emb, embnorm, hist, lossacc);
    vq_kernel<<<1024, 256, 0, stream>>>(z, emb, embnorm, out, hist, lossacc);
    fin_kernel<<<1, 512, 0, stream>>>(hist, lossacc, out);
}

// Round 12
// 476.364 us; speedup vs baseline: 1.3716x; 1.0064x over previous
//
#include <hip/hip_runtime.h>

// Output layout (float*, concatenated in reference return order):
//   z_q_out : 64*64*64*64 = 16,777,216 floats  @ [0, 16777216)
//   loss    : 1 float                          @ [16777216]
//   idx_out : 64*64*64   =    262,144 floats   @ [16777217, 17039361)
//   perplex : 1 float                          @ [17039361]
#define ZQ_OFF    0
#define LOSS_OFF  16777216
#define IDX_OFF   16777217
#define PERP_OFF  17039361

#define NPOINTS   262144      // B*H*W
#define NELEM     16777216    // B*C*H*W

// ws layout: [0,2048) float embnorm[512]; [2048,4096) int hist[512]; [4096,4104) double lossacc

typedef float sf16 __attribute__((ext_vector_type(16)));
typedef float sf4  __attribute__((ext_vector_type(4)));

// 4 codebook rows x 16 d-values -> 64 SGPRs, plus (first chunk) 4 embnorms.
// The s_waitcnt lives INSIDE the asm so consumers can never be scheduled
// before the data lands (SMEM returns out-of-order; only lgkmcnt(0) is safe).
#define SLOAD5(E0,E1,E2,E3,EN,GB,NB,O0,O1,O2,O3)       \
  asm("s_load_dwordx16 %0, %5, " O0 "\n\t"             \
      "s_load_dwordx16 %1, %5, " O1 "\n\t"             \
      "s_load_dwordx16 %2, %5, " O2 "\n\t"             \
      "s_load_dwordx16 %3, %5, " O3 "\n\t"             \
      "s_load_dwordx4  %4, %6, 0x0\n\t"                \
      "s_waitcnt lgkmcnt(0)"                           \
      : "=s"(E0), "=s"(E1), "=s"(E2), "=s"(E3), "=s"(EN) \
      : "s"(GB), "s"(NB))

#define SLOAD4(E0,E1,E2,E3,GB,O0,O1,O2,O3)             \
  asm("s_load_dwordx16 %0, %4, " O0 "\n\t"             \
      "s_load_dwordx16 %1, %4, " O1 "\n\t"             \
      "s_load_dwordx16 %2, %4, " O2 "\n\t"             \
      "s_load_dwordx16 %3, %4, " O3 "\n\t"             \
      "s_waitcnt lgkmcnt(0)"                           \
      : "=s"(E0), "=s"(E1), "=s"(E2), "=s"(E3)         \
      : "s"(GB))

// 16 d-steps x 4 codes; SGPR operand rides in the v_fmac scalar slot (free).
// Per-accumulator chain order (d ascending) identical to the R3 kernel.
#define FMACHUNK(E0,E1,E2,E3,DC)                        \
  { _Pragma("unroll")                                   \
    for (int j = 0; j < 16; ++j) {                      \
      float v = zv[(DC) + j];                           \
      a0 += v * E0[j];                                  \
      a1 += v * E1[j];                                  \
      a2 += v * E2[j];                                  \
      a3 += v * E3[j];                                  \
    } }

// ---------------- kernel 0: codebook norms + zero accumulators ----------------
__global__ void prep_kernel(const float* __restrict__ emb,
                            float* __restrict__ embnorm,
                            int* __restrict__ hist,
                            double* __restrict__ lossacc) {
    int k = threadIdx.x;          // 512 threads, 1 block
    hist[k] = 0;
    const float* e = emb + (k << 6);
    float s = 0.f;
    #pragma unroll
    for (int d = 0; d < 64; ++d) s += e[d] * e[d];
    embnorm[k] = s;
    if (k == 0) *lossacc = 0.0;
}

// ---------------- kernel 1: argmin + z_q(STE) + idx + hist + loss partials ----------------
// R10 lesson: ANY source-level restructure of the distance math changes
// codegen rounding and flips argmin near-ties (idx absmax 50, FAILED).
// This kernel is the R9 source (passed, absmax 0.0) + ONE runtime-no-op
// change: zv[d] pinned via identity asm so the compiler cannot rematerialize
// it as global reloads inside the sweep (R9: VGPR=56 < 64 needed -> remat ->
// VALU busy 284us vs 109us FMA floor). Pin forces register residency;
// waves_per_eu(4,4) provides the 128-VGPR budget. Values are untouched.
__global__ __launch_bounds__(256)
__attribute__((amdgpu_waves_per_eu(4, 4)))
void vq_kernel(const float* __restrict__ z,
               const float* __restrict__ emb,
               const float* __restrict__ embnorm,
               float* __restrict__ out,
               int* __restrict__ hist,
               double* __restrict__ lossacc) {
    // 1024 blocks x 256 threads; thread = one (b,h,w) point; block = b fixed, 4 h-rows.
    const int bid = blockIdx.x;
    const int b  = bid >> 4;                 // 64 b values
    const int h  = ((bid & 15) << 2) + (threadIdx.x >> 6); // 4 rows per block
    const int w  = threadIdx.x & 63;

    // Load this point's 64-dim vector; lanes (w=0..63) consecutive -> coalesced per channel.
    const float* zp = z + ((size_t)b << 18) + ((size_t)h << 6) + w;  // + c*4096
    float zv[64];
    float z2 = 0.f;
    #pragma unroll
    for (int d = 0; d < 64; ++d) {
        float v = zp[(size_t)d << 12];
        zv[d] = v;
        z2 += v * v;
    }
    // Pin: identity asm makes each zv[d] non-rematerializable -> must stay
    // in a VGPR from here to last use. Runtime no-op; numerics unchanged.
    #pragma unroll
    for (int d = 0; d < 64; ++d) {
        asm volatile("" : "+v"(zv[d]));
    }

    float best = 3.4e38f;
    int   bidx = 0;
    #pragma unroll 1
    for (int k0 = 0; k0 < 512; k0 += 4) {
        const float* gb = emb + ((size_t)k0 << 6);   // uniform: SGPR pair
        const float* nb = embnorm + k0;              // uniform: SGPR pair
        sf16 E0, E1, E2, E3;
        sf4  EN;
        float a0 = 0.f, a1 = 0.f, a2 = 0.f, a3 = 0.f;

        SLOAD5(E0, E1, E2, E3, EN, gb, nb, "0x0",  "0x100", "0x200", "0x300");
        FMACHUNK(E0, E1, E2, E3, 0)
        SLOAD4(E0, E1, E2, E3, gb,        "0x40", "0x140", "0x240", "0x340");
        FMACHUNK(E0, E1, E2, E3, 16)
        SLOAD4(E0, E1, E2, E3, gb,        "0x80", "0x180", "0x280", "0x380");
        FMACHUNK(E0, E1, E2, E3, 32)
        SLOAD4(E0, E1, E2, E3, gb,        "0xC0", "0x1C0", "0x2C0", "0x3C0");
        FMACHUNK(E0, E1, E2, E3, 48)

        // same formula as reference: ||z||^2 + ||e||^2 - 2 z.e
        float d0 = z2 + EN[0] - 2.f * a0;
        float d1 = z2 + EN[1] - 2.f * a1;
        float d2 = z2 + EN[2] - 2.f * a2;
        float d3 = z2 + EN[3] - 2.f * a3;
        // strict < in ascending k preserves first-min (reference argmin tie rule)
        if (d0 < best) { best = d0; bidx = k0;     }
        if (d1 < best) { best = d1; bidx = k0 + 1; }
        if (d2 < best) { best = d2; bidx = k0 + 2; }
        if (d3 < best) { best = d3; bidx = k0 + 3; }
    }

    // idx output (as float) + histogram
    const size_t pidx = ((size_t)b << 12) + ((size_t)h << 6) + w;
    __builtin_nontemporal_store((float)bidx, &out[IDX_OFF + pidx]);
    atomicAdd(&hist[bidx], 1);

    // z_q straight-through write + loss partial.
    // Replicate reference rounding: diff = e - z (fp32); out = z + diff (fp32); loss term = diff^2.
    const float* eb = emb + ((size_t)bidx << 6);   // per-lane gather, L2-resident
    float* zqout = out + ((size_t)b << 18) + ((size_t)h << 6) + w;
    float lsum = 0.f;
    #pragma unroll
    for (int d = 0; d < 64; ++d) {
        float e    = eb[d];
        float diff = e - zv[d];
        lsum += diff * diff;
        // nt store: don't let the 64 MB z_q stream evict emb/z from L1/L2
        __builtin_nontemporal_store(zv[d] + diff, &zqout[(size_t)d << 12]);
    }

    // block-reduce lsum -> one double atomic per block
    #pragma unroll
    for (int off = 32; off; off >>= 1) lsum += __shfl_down(lsum, off, 64);
    __shared__ float wsum[4];
    if ((threadIdx.x & 63) == 0) wsum[threadIdx.x >> 6] = lsum;
    __syncthreads();
    if (threadIdx.x == 0) {
        atomicAdd(lossacc, (double)(wsum[0] + wsum[1] + wsum[2] + wsum[3]));
    }
}

// ---------------- kernel 2: finalize loss + perplexity ----------------
__global__ void fin_kernel(const int* __restrict__ hist,
                           const double* __restrict__ lossacc,
                           float* __restrict__ out) {
    int k = threadIdx.x;   // 512 threads, 1 block
    float avg = (float)hist[k] * (1.0f / 262144.0f);   // exact: cnt / 2^18
    float t = avg * logf(avg + 1e-10f);
    #pragma unroll
    for (int off = 32; off; off >>= 1) t += __shfl_down(t, off, 64);
    __shared__ float s[8];
    if ((k & 63) == 0) s[k >> 6] = t;
    __syncthreads();
    if (k == 0) {
        float S = 0.f;
        #pragma unroll
        for (int i = 0; i < 8; ++i) S += s[i];
        out[PERP_OFF] = expf(-S);
        out[LOSS_OFF] = (float)(1.25 * (*lossacc) / (double)NELEM);
    }
}

extern "C" void kernel_launch(void* const* d_in, const int* in_sizes, int n_in,
                              void* d_out, int out_size, void* d_ws, size_t ws_size,
                              hipStream_t stream) {
    const float* z   = (const float*)d_in[0];
    const float* emb = (const float*)d_in[1];
    float* out = (float*)d_out;

    float*  embnorm = (float*)d_ws;
    int*    hist    = (int*)((char*)d_ws + 2048);
    double* lossacc = (double*)((char*)d_ws + 4096);

    prep_kernel<<<1, 512, 0, stream>>>(emb, embnorm, hist, lossacc);
    vq_kernel<<<1024, 256, 0, stream>>>(z, emb, embnorm, out, hist, lossacc);
    fin_kernel<<<1, 512, 0, stream>>>(hist, lossacc, out);
}

// Round 16
// 444.966 us; speedup vs baseline: 1.4684x; 1.0706x over previous
//
#include <hip/hip_runtime.h>

// Output layout (float*, concatenated in reference return order):
//   z_q_out : 64*64*64*64 = 16,777,216 floats  @ [0, 16777216)
//   loss    : 1 float                          @ [16777216]
//   idx_out : 64*64*64   =    262,144 floats   @ [16777217, 17039361)
//   perplex : 1 float                          @ [17039361]
#define ZQ_OFF    0
#define LOSS_OFF  16777216
#define IDX_OFF   16777217
#define PERP_OFF  17039361

#define NPOINTS   262144      // B*H*W
#define NELEM     16777216    // B*C*H*W

// ws layout: [0,2048) float embnorm[512]; [2048,4096) int hist[512]; [4096,4104) double lossacc

typedef float sf16 __attribute__((ext_vector_type(16)));
typedef float sf4  __attribute__((ext_vector_type(4)));

// 4 codebook rows x 16 d-values -> 64 SGPRs, plus (first chunk) 4 embnorms.
// s_waitcnt INSIDE the asm: consumers can never be scheduled before data lands.
#define SLOAD5(E0,E1,E2,E3,EN,GB,NB,O0,O1,O2,O3)       \
  asm("s_load_dwordx16 %0, %5, " O0 "\n\t"             \
      "s_load_dwordx16 %1, %5, " O1 "\n\t"             \
      "s_load_dwordx16 %2, %5, " O2 "\n\t"             \
      "s_load_dwordx16 %3, %5, " O3 "\n\t"             \
      "s_load_dwordx4  %4, %6, 0x0\n\t"                \
      "s_waitcnt lgkmcnt(0)"                           \
      : "=s"(E0), "=s"(E1), "=s"(E2), "=s"(E3), "=s"(EN) \
      : "s"(GB), "s"(NB))

#define SLOAD4(E0,E1,E2,E3,GB,O0,O1,O2,O3)             \
  asm("s_load_dwordx16 %0, %4, " O0 "\n\t"             \
      "s_load_dwordx16 %1, %4, " O1 "\n\t"             \
      "s_load_dwordx16 %2, %4, " O2 "\n\t"             \
      "s_load_dwordx16 %3, %4, " O3 "\n\t"             \
      "s_waitcnt lgkmcnt(0)"                           \
      : "=s"(E0), "=s"(E1), "=s"(E2), "=s"(E3)         \
      : "s"(GB))

// 16 d-steps x 4 codes; SGPR operand rides in the v_fmac scalar slot.
// Per-accumulator chain order (d ascending) identical to R3/R9/R12 (passed).
#define FMACHUNK(E0,E1,E2,E3,DC)                        \
  { _Pragma("unroll")                                   \
    for (int j = 0; j < 16; ++j) {                      \
      float v = zv[(DC) + j];                           \
      a0 += v * E0[j];                                  \
      a1 += v * E1[j];                                  \
      a2 += v * E2[j];                                  \
      a3 += v * E3[j];                                  \
    } }

// ---------------- kernel 0: codebook norms + zero accumulators ----------------
__global__ void prep_kernel(const float* __restrict__ emb,
                            float* __restrict__ embnorm,
                            int* __restrict__ hist,
                            double* __restrict__ lossacc) {
    int k = threadIdx.x;          // 512 threads, 1 block
    hist[k] = 0;
    const float* e = emb + (k << 6);
    float s = 0.f;
    #pragma unroll
    for (int d = 0; d < 64; ++d) s += e[d] * e[d];
    embnorm[k] = s;
    if (k == 0) *lossacc = 0.0;
}

// ---------------- kernel 1: argmin + z_q(STE) + idx + hist + loss partials ----------------
// R13 compile fail: kbase derived from threadIdx.x -> compiler can't prove
// wave-uniformity -> emb+kbase address went vector -> "s" asm constraint
// unsatisfiable (s_load with v[] base). Fix: half/row via readfirstlane
// (value-identical: tid>>6 is constant across a wave) -> address chain
// scalarizes exactly as in the passing R9/R12 code.
// Structure (R12 plan): 2 threads per point in different waves, each sweeps
// 256 codes with the IDENTICAL compiled loop (runtime kbase SGPR -> same
// machine code -> same distance bits). Combine via LDS, strict < (ties keep
// half0's lower k) == ascending-k first-min. 8192 waves = 32 waves/CU.
__global__ __launch_bounds__(256)
void vq_kernel(const float* __restrict__ z,
               const float* __restrict__ emb,
               const float* __restrict__ embnorm,
               float* __restrict__ out,
               int* __restrict__ hist,
               double* __restrict__ lossacc) {
    // 2048 blocks x 256 threads; block = 128 points (2 h-rows x 64 w) x 2 halves.
    // wave 0: row0 half0, wave 1: row1 half0, wave 2: row0 half1, wave 3: row1 half1.
    const int tid  = threadIdx.x;
    const int lane = tid & 63;           // = w
    // wave id: uniform across the wave BY CONSTRUCTION via readfirstlane,
    // so the compiler keeps everything derived from it in SGPRs.
    const int wv   = __builtin_amdgcn_readfirstlane(tid >> 6);   // 0..3
    const int row  = wv & 1;
    const int half = wv >> 1;
    const int bid  = blockIdx.x;
    const int b    = bid >> 5;                    // 64 b values
    const int h    = ((bid & 31) << 1) | row;     // 64 h values
    const int w    = lane;

    __shared__ float sd[128];
    __shared__ int   sk[128];
    __shared__ float wsum[2];
    const int slot = (row << 6) | lane;

    // Load this point's 64-dim vector; lanes (w=0..63) consecutive -> coalesced.
    const float* zp = z + ((size_t)b << 18) + ((size_t)h << 6) + w;  // + c*4096
    float zv[64];
    float z2 = 0.f;
    #pragma unroll
    for (int d = 0; d < 64; ++d) {
        float v = zp[(size_t)d << 12];
        zv[d] = v;
        z2 += v * v;
    }
    // Pin (proven numerics-neutral in R12): forbid remat of zv values.
    #pragma unroll
    for (int d = 0; d < 64; ++d) {
        asm volatile("" : "+v"(zv[d]));
    }

    // Sweep this half's 256 codes; identical machine loop for both halves.
    const int kbase = half << 8;          // SGPR (half is readfirstlane-derived)
    float best = 3.4e38f;
    int   bidx = kbase;
    #pragma unroll 1
    for (int k0 = kbase; k0 < kbase + 256; k0 += 4) {
        const float* gb = emb + ((size_t)k0 << 6);   // wave-uniform: SGPR pair
        const float* nb = embnorm + k0;              // wave-uniform: SGPR pair
        sf16 E0, E1, E2, E3;
        sf4  EN;
        float a0 = 0.f, a1 = 0.f, a2 = 0.f, a3 = 0.f;

        SLOAD5(E0, E1, E2, E3, EN, gb, nb, "0x0",  "0x100", "0x200", "0x300");
        FMACHUNK(E0, E1, E2, E3, 0)
        SLOAD4(E0, E1, E2, E3, gb,        "0x40", "0x140", "0x240", "0x340");
        FMACHUNK(E0, E1, E2, E3, 16)
        SLOAD4(E0, E1, E2, E3, gb,        "0x80", "0x180", "0x280", "0x380");
        FMACHUNK(E0, E1, E2, E3, 32)
        SLOAD4(E0, E1, E2, E3, gb,        "0xC0", "0x1C0", "0x2C0", "0x3C0");
        FMACHUNK(E0, E1, E2, E3, 48)

        // same formula as reference: ||z||^2 + ||e||^2 - 2 z.e
        float d0 = z2 + EN[0] - 2.f * a0;
        float d1 = z2 + EN[1] - 2.f * a1;
        float d2 = z2 + EN[2] - 2.f * a2;
        float d3 = z2 + EN[3] - 2.f * a3;
        // strict < in ascending k preserves first-min (reference argmin tie rule)
        if (d0 < best) { best = d0; bidx = k0;     }
        if (d1 < best) { best = d1; bidx = k0 + 1; }
        if (d2 < best) { best = d2; bidx = k0 + 2; }
        if (d3 < best) { best = d3; bidx = k0 + 3; }
    }

    // Combine halves: half1 publishes, half0 takes on STRICT < only
    // (equal -> half0's k, which is the lower index == first-min rule).
    if (half == 1) { sd[slot] = best; sk[slot] = bidx; }
    __syncthreads();

    float lsum = 0.f;
    if (half == 0) {
        float db = sd[slot];
        int   kb = sk[slot];
        if (db < best) { best = db; bidx = kb; }

        // idx output (as float) + histogram
        const size_t pidx = ((size_t)b << 12) + ((size_t)h << 6) + w;
        __builtin_nontemporal_store((float)bidx, &out[IDX_OFF + pidx]);
        atomicAdd(&hist[bidx], 1);

        // z_q straight-through write + loss partial.
        // diff = e - z (fp32); out = z + diff (fp32); loss term = diff^2.
        const float* eb = emb + ((size_t)bidx << 6);   // per-lane gather, L2-resident
        float* zqout = out + ((size_t)b << 18) + ((size_t)h << 6) + w;
        #pragma unroll
        for (int d = 0; d < 64; ++d) {
            float e    = eb[d];
            float diff = e - zv[d];
            lsum += diff * diff;
            // nt store: don't let the 64 MB z_q stream evict emb/z from L1/L2
            __builtin_nontemporal_store(zv[d] + diff, &zqout[(size_t)d << 12]);
        }

        // wave reduce then per-row partial
        #pragma unroll
        for (int off = 32; off; off >>= 1) lsum += __shfl_down(lsum, off, 64);
        if (lane == 0) wsum[row] = lsum;
    }
    __syncthreads();
    if (tid == 0) {
        atomicAdd(lossacc, (double)(wsum[0] + wsum[1]));
    }
}

// ---------------- kernel 2: finalize loss + perplexity ----------------
__global__ void fin_kernel(const int* __restrict__ hist,
                           const double* __restrict__ lossacc,
                           float* __restrict__ out) {
    int k = threadIdx.x;   // 512 threads, 1 block
    float avg = (float)hist[k] * (1.0f / 262144.0f);   // exact: cnt / 2^18
    float t = avg * logf(avg + 1e-10f);
    #pragma unroll
    for (int off = 32; off; off >>= 1) t += __shfl_down(t, off, 64);
    __shared__ float s[8];
    if ((k & 63) == 0) s[k >> 6] = t;
    __syncthreads();
    if (k == 0) {
        float S = 0.f;
        #pragma unroll
        for (int i = 0; i < 8; ++i) S += s[i];
        out[PERP_OFF] = expf(-S);
        out[LOSS_OFF] = (float)(1.25 * (*lossacc) / (double)NELEM);
    }
}

extern "C" void kernel_launch(void* const* d_in, const int* in_sizes, int n_in,
                              void* d_out, int out_size, void* d_ws, size_t ws_size,
                              hipStream_t stream) {
    const float* z   = (const float*)d_in[0];
    const float* emb = (const float*)d_in[1];
    float* out = (float*)d_out;

    float*  embnorm = (float*)d_ws;
    int*    hist    = (int*)((char*)d_ws + 2048);
    double* lossacc = (double*)((char*)d_ws + 4096);

    prep_kernel<<<1, 512, 0, stream>>>(emb, embnorm, hist, lossacc);
    vq_kernel<<<2048, 256, 0, stream>>>(z, emb, embnorm, out, hist, lossacc);
    fin_kernel<<<1, 512, 0, stream>>>(hist, lossacc, out);
}